// Round 6
// baseline (635.610 us; speedup 1.0000x reference)
//
#include <hip/hip_runtime.h>
#include <hip/hip_fp16.h>

#define HS 1024
#define TT 2048

typedef _Float16 half8 __attribute__((ext_vector_type(8)));
typedef float floatx4 __attribute__((ext_vector_type(4)));

// Async global->LDS DMA, 16B per lane. LDS dest = wave-uniform base + lane*16.
__device__ __forceinline__ void dma16(const _Float16* g, _Float16* l) {
    __builtin_amdgcn_global_load_lds(
        (const __attribute__((address_space(1))) unsigned int*)g,
        (__attribute__((address_space(3))) unsigned int*)l, 16, 0, 0);
}

// K1: merged prep. Blocks 0..8191: dproj[n*1024+a] = bias[a]+sum_e h_dec[n,e]*W[a,e]
// (one wave per (n,a)). Blocks 8192..9215: We16 = (fp16) W[:, 1024:].
__global__ __launch_bounds__(256) void k_prep(const float* __restrict__ h_dec,
                                              const float* __restrict__ W,
                                              const float* __restrict__ bias,
                                              float* __restrict__ dproj,
                                              _Float16* __restrict__ We16) {
    int b = blockIdx.x;
    if (b < 8192) {
        int wid = b * 4 + (threadIdx.x >> 6);   // 0..32767
        int lane = threadIdx.x & 63;
        int n = wid >> 10, a = wid & 1023;
        const float4* hd = reinterpret_cast<const float4*>(h_dec + (size_t)n * HS);
        const float4* wr = reinterpret_cast<const float4*>(W + (size_t)a * 2048);
        float s = 0.f;
#pragma unroll
        for (int i = 0; i < 4; ++i) {
            float4 h = hd[lane + i * 64];
            float4 w = wr[lane + i * 64];
            s += h.x * w.x + h.y * w.y + h.z * w.z + h.w * w.w;
        }
        for (int off = 32; off; off >>= 1) s += __shfl_xor(s, off);
        if (lane == 0) dproj[wid] = bias[a] + s;
    } else {
        int idx4 = ((b - 8192) * 256 + threadIdx.x) * 4;
        int a = idx4 >> 10;
        int e = idx4 & 1023;
        float4 f = *reinterpret_cast<const float4*>(W + (size_t)a * 2048 + 1024 + e);
        _Float16 h0 = (_Float16)f.x, h1 = (_Float16)f.y;
        _Float16 h2 = (_Float16)f.z, h3 = (_Float16)f.w;
        ushort4 p;
        p.x = *(unsigned short*)&h0; p.y = *(unsigned short*)&h1;
        p.z = *(unsigned short*)&h2; p.w = *(unsigned short*)&h3;
        *reinterpret_cast<ushort4*>(We16 + idx4) = p;
    }
}

// K2: h_enc16 = (fp16) h_enc, streaming, 8 elems/thread.
__global__ __launch_bounds__(256) void k_cvtA(const float* __restrict__ h_enc,
                                              _Float16* __restrict__ h_enc16) {
    size_t idx = ((size_t)blockIdx.x * 256 + threadIdx.x) * 8;
    const float4* g = reinterpret_cast<const float4*>(h_enc + idx);
    float4 f0 = g[0], f1 = g[1];
    _Float16 h[8];
    h[0] = (_Float16)f0.x; h[1] = (_Float16)f0.y; h[2] = (_Float16)f0.z; h[3] = (_Float16)f0.w;
    h[4] = (_Float16)f1.x; h[5] = (_Float16)f1.y; h[6] = (_Float16)f1.z; h[7] = (_Float16)f1.w;
    *reinterpret_cast<uint4*>(h_enc16 + idx) = *reinterpret_cast<uint4*>(&h[0]);
}

// K3: fused score GEMM. Triple-buffered DMA staging, prefetch distance 2,
// raw s_barrier + s_waitcnt vmcnt(6) so prefetch loads stay in flight across
// the barrier (AITER-style; __syncthreads would drain vmcnt to 0).
// Block: 128 t-rows of one n; 4 a-passes x 32 k-iters (BK=32).
// LDS rows 32 halves (4 granules), swizzle pg = quad ^ ((row>>1)&3).
__global__ __launch_bounds__(256, 2) void k_score(const _Float16* __restrict__ h_enc16,
                                                  const _Float16* __restrict__ We16,
                                                  const float* __restrict__ dproj,
                                                  const float* __restrict__ v,
                                                  float* __restrict__ scores) {
    __shared__ _Float16 Asb[3][128 * 32];   // 3 x 8 KB
    __shared__ _Float16 Bsb[3][256 * 32];   // 3 x 16 KB
    __shared__ float s_acc[128];

    const int tid = threadIdx.x;
    const int n  = blockIdx.x >> 4;
    const int t0 = (blockIdx.x & 15) << 7;

    if (tid < 128) s_acc[tid] = 0.0f;

    const int w    = tid >> 6;          // wave 0..3 (uniform)
    const int lane = tid & 63;
    const int wm = w >> 1, wn = w & 1;  // 2x2 wave grid; wave tile 64t x 128a
    const int col = lane & 15, quad = lane >> 4;

    // DMA source mapping: one chunk = 16 rows x 32 halves (1 KB).
    const int lrow = lane >> 2;
    const int lg   = (lane & 3) ^ ((lrow >> 1) & 3);
    const size_t goff = (size_t)lrow * HS + lg * 8;   // halves

    const _Float16* gA = h_enc16 + (size_t)(n * TT + t0) * HS + goff;
    const _Float16* gB = We16 + goff;

    floatx4 acc[4][8];

    // 6 DMA chunks (2 A + 4 B) for flat iteration `src` into buffer p.
    auto issue = [&](int src, int p) {
        const int a0 = (src >> 5) << 8;
        const int kk = (src & 31) << 5;
        const _Float16* gAi = gA + kk;
        const _Float16* gBi = gB + (size_t)a0 * HS + kk;
#pragma unroll
        for (int j = 0; j < 2; ++j)
            dma16(gAi + (size_t)(w * 32 + j * 16) * HS, &Asb[p][(w * 2 + j) * 512]);
#pragma unroll
        for (int j = 0; j < 4; ++j)
            dma16(gBi + (size_t)(w * 64 + j * 16) * HS, &Bsb[p][(w * 4 + j) * 512]);
    };

    issue(0, 0);
    issue(1, 1);

    for (int pass = 0; pass < 4; ++pass) {
#pragma unroll
        for (int mi = 0; mi < 4; ++mi)
#pragma unroll
            for (int ni = 0; ni < 8; ++ni)
                acc[mi][ni] = (floatx4)0.0f;

        for (int kit = 0; kit < 32; ++kit) {
            const int it = pass * 32 + kit;
            const int p = it % 3;

            // Wait only for the oldest 6 DMAs (= tile `it`); keep 12 in flight.
            asm volatile("s_waitcnt vmcnt(6)" ::: "memory");
            asm volatile("s_barrier" ::: "memory");

            {   // prefetch tile it+2 (clamped re-issue keeps vmcnt uniform)
                const int nx = it + 2;
                issue(nx < 128 ? nx : 127, nx % 3);
            }

            const _Float16* Ab = Asb[p];
            const _Float16* Bb = Bsb[p];
            half8 af[4], bf[8];
#pragma unroll
            for (int mi = 0; mi < 4; ++mi) {
                const int r = wm * 64 + mi * 16 + col;
                af[mi] = *reinterpret_cast<const half8*>(
                    &Ab[r * 32 + ((quad ^ ((r >> 1) & 3)) << 3)]);
            }
#pragma unroll
            for (int ni = 0; ni < 8; ++ni) {
                const int r = wn * 128 + ni * 16 + col;
                bf[ni] = *reinterpret_cast<const half8*>(
                    &Bb[r * 32 + ((quad ^ ((r >> 1) & 3)) << 3)]);
            }
#pragma unroll
            for (int mi = 0; mi < 4; ++mi)
#pragma unroll
                for (int ni = 0; ni < 8; ++ni)
                    acc[mi][ni] = __builtin_amdgcn_mfma_f32_16x16x32_f16(
                        af[mi], bf[ni], acc[mi][ni], 0, 0, 0);
        }

        // epilogue: s_acc[t] += sum_a v[a]*tanh(C[t][a] + dproj[n,a])
        // C/D layout: col = lane&15 (a), row = quad*4+reg (t)
        {
            const int a0 = pass << 8;
            float vv[8], dd[8];
#pragma unroll
            for (int ni = 0; ni < 8; ++ni) {
                int a = a0 + wn * 128 + ni * 16 + col;
                vv[ni] = v[a];
                dd[ni] = dproj[n * HS + a];
            }
#pragma unroll
            for (int mi = 0; mi < 4; ++mi) {
#pragma unroll
                for (int rg = 0; rg < 4; ++rg) {
                    float s = 0.0f;
#pragma unroll
                    for (int ni = 0; ni < 8; ++ni) {
                        float x = acc[mi][ni][rg] + dd[ni];
                        float e2 = __expf(2.0f * x);
                        float th = 1.0f - 2.0f * __builtin_amdgcn_rcpf(e2 + 1.0f);
                        s += vv[ni] * th;
                    }
                    s += __shfl_xor(s, 8);
                    s += __shfl_xor(s, 4);
                    s += __shfl_xor(s, 2);
                    s += __shfl_xor(s, 1);
                    if (col == 0)
                        atomicAdd(&s_acc[wm * 64 + mi * 16 + quad * 4 + rg], s);
                }
            }
        }
    }
    __syncthreads();
    if (tid < 128) scores[(size_t)n * TT + t0 + tid] = s_acc[tid];
}

// K4: masked softmax per row, in place.
__global__ __launch_bounds__(256) void k_softmax(float* __restrict__ wout,
                                                 const int* __restrict__ lens) {
    __shared__ float red[4];
    __shared__ float red2[4];
    int n = blockIdx.x, tid = threadIdx.x;
    int len = lens[n];
    float* row = wout + (size_t)n * TT;
    float sv[8];
    float m = -3.0e38f;
#pragma unroll
    for (int i = 0; i < 8; ++i) {
        int t = tid + i * 256;
        float s = row[t];
        s = (t < len) ? s : -1.0e10f;
        sv[i] = s;
        m = fmaxf(m, s);
    }
    for (int off = 1; off <= 32; off <<= 1) m = fmaxf(m, __shfl_xor(m, off));
    if ((tid & 63) == 0) red[tid >> 6] = m;
    __syncthreads();
    m = fmaxf(fmaxf(red[0], red[1]), fmaxf(red[2], red[3]));
    float sum = 0.f, es[8];
#pragma unroll
    for (int i = 0; i < 8; ++i) { es[i] = __expf(sv[i] - m); sum += es[i]; }
    for (int off = 1; off <= 32; off <<= 1) sum += __shfl_xor(sum, off);
    if ((tid & 63) == 0) red2[tid >> 6] = sum;
    __syncthreads();
    sum = red2[0] + red2[1] + red2[2] + red2[3];
    float rinv = 1.0f / sum;
#pragma unroll
    for (int i = 0; i < 8; ++i) row[tid + i * 256] = es[i] * rinv;
}

// K5: ctx[n,e] = sum_t w[n,t] * h_enc16[n,t,e]; t-split via atomics.
__global__ __launch_bounds__(256) void k_ctx(const _Float16* __restrict__ h_enc16,
                                             const float* __restrict__ wts,
                                             float* __restrict__ ctx) {
    __shared__ float red[8][257];     // padded: conflict-free stores/loads
    int b = blockIdx.x;               // 512 blocks: n(32) x ec(4) x ts(4)
    int n  = b >> 4;
    int ec = (b >> 2) & 3;
    int ts = b & 3;
    int tid = threadIdx.x;
    int q = tid & 31, tg = tid >> 5;
    int e = ec * 256 + q * 8;
    float acc[8];
#pragma unroll
    for (int j = 0; j < 8; ++j) acc[j] = 0.f;
    const float* wrow = wts + (size_t)n * TT;
    for (int t = ts * 512 + tg; t < ts * 512 + 512; t += 8) {
        float w = wrow[t];
        uint4 raw = *reinterpret_cast<const uint4*>(
            h_enc16 + ((size_t)(n * TT + t)) * HS + e);
        const _Float16* hp = reinterpret_cast<const _Float16*>(&raw);
#pragma unroll
        for (int j = 0; j < 8; ++j) acc[j] += w * (float)hp[j];
    }
#pragma unroll
    for (int j = 0; j < 8; ++j) red[j][tid] = acc[j];
    __syncthreads();
    if (tid < 32) {
        float s[8];
#pragma unroll
        for (int j = 0; j < 8; ++j) s[j] = red[j][tid];
        for (int g = 1; g < 8; ++g)
#pragma unroll
            for (int j = 0; j < 8; ++j) s[j] += red[j][g * 32 + tid];
        float* dst = ctx + (size_t)n * HS + ec * 256 + tid * 8;
#pragma unroll
        for (int j = 0; j < 8; ++j) atomicAdd(dst + j, s[j]);
    }
}

// ---------- slow-but-correct fallback (only if ws is too small; unexpected) ----------
__global__ __launch_bounds__(256) void k_score_naive(const float* __restrict__ h_enc,
                                                     const float* __restrict__ W,
                                                     const float* __restrict__ dproj,
                                                     const float* __restrict__ v,
                                                     float* __restrict__ scores) {
    int gw = blockIdx.x * 4 + (threadIdx.x >> 6);   // wave per (n,t)
    int lane = threadIdx.x & 63;
    int n = gw >> 11, t = gw & 2047;
    const float4* he = reinterpret_cast<const float4*>(h_enc + ((size_t)(n * TT + t)) * HS);
    float4 hv[4];
#pragma unroll
    for (int i = 0; i < 4; ++i) hv[i] = he[lane + i * 64];
    float s = 0.f;
    for (int a = 0; a < 1024; ++a) {
        const float4* wr = reinterpret_cast<const float4*>(W + (size_t)a * 2048 + 1024);
        float d = 0.f;
#pragma unroll
        for (int i = 0; i < 4; ++i) {
            float4 wv = wr[lane + i * 64];
            d += hv[i].x * wv.x + hv[i].y * wv.y + hv[i].z * wv.z + hv[i].w * wv.w;
        }
        for (int off = 32; off; off >>= 1) d += __shfl_xor(d, off);
        s += v[a] * tanhf(d + dproj[n * HS + a]);
    }
    if (lane == 0) scores[(size_t)n * TT + t] = s;
}

__global__ __launch_bounds__(256) void k_ctx_naive(const float* __restrict__ h_enc,
                                                   const float* __restrict__ wts,
                                                   float* __restrict__ ctx) {
    int n = blockIdx.x;
    int e = threadIdx.x * 4;
    float4 a = make_float4(0.f, 0.f, 0.f, 0.f);
    const float* wrow = wts + (size_t)n * TT;
    for (int t = 0; t < TT; ++t) {
        float w = wrow[t];
        float4 h = *reinterpret_cast<const float4*>(h_enc + ((size_t)(n * TT + t)) * HS + e);
        a.x += w * h.x; a.y += w * h.y; a.z += w * h.z; a.w += w * h.w;
    }
    *reinterpret_cast<float4*>(ctx + (size_t)n * HS + e) = a;
}

extern "C" void kernel_launch(void* const* d_in, const int* in_sizes, int n_in,
                              void* d_out, int out_size, void* d_ws, size_t ws_size,
                              hipStream_t stream) {
    const float* h_dec    = (const float*)d_in[0];
    const float* h_enc    = (const float*)d_in[1];
    const int*   src_lens = (const int*)d_in[2];
    const float* W = (const float*)d_in[3];
    const float* b = (const float*)d_in[4];
    const float* v = (const float*)d_in[5];

    float* out = (float*)d_out;
    float* ctx = out;                 // 32*1024
    float* wts = out + 32 * 1024;     // 32*2048 (scores, then weights in place)

    float*    dproj   = (float*)d_ws;                                  // 128 KB
    _Float16* We16    = (_Float16*)((char*)d_ws + 131072);             // 2 MB
    _Float16* h_enc16 = (_Float16*)((char*)d_ws + 131072 + 2097152);   // 128 MB
    const size_t need = 131072 + 2097152 + (size_t)32 * TT * HS * 2;

    if (ws_size >= need) {
        (void)hipMemsetAsync(ctx, 0, 32 * 1024 * sizeof(float), stream);
        k_prep<<<9216, 256, 0, stream>>>(h_dec, W, b, dproj, We16);
        k_cvtA<<<32768, 256, 0, stream>>>(h_enc, h_enc16);
        k_score<<<512, 256, 0, stream>>>(h_enc16, We16, dproj, v, wts);
        k_softmax<<<32, 256, 0, stream>>>(wts, src_lens);
        k_ctx<<<512, 256, 0, stream>>>(h_enc16, wts, ctx);
    } else {
        k_prep<<<9216, 256, 0, stream>>>(h_dec, W, b, dproj, We16);
        k_score_naive<<<16384, 256, 0, stream>>>(h_enc, W, dproj, v, wts);
        k_softmax<<<32, 256, 0, stream>>>(wts, src_lens);
        k_ctx_naive<<<32, 256, 0, stream>>>(h_enc, wts, ctx);
    }
}